// Round 2
// baseline (636565.137 us; speedup 1.0000x reference)
//
#include <hip/hip_runtime.h>
#include <cstdint>
#include <cstddef>

#define TT 65536
#define KK 512
#define NEGV (-10000.0f)
#define SEG 256
#define NSEG 256  // TT/SEG

typedef unsigned short u16;
typedef unsigned int   u32;
typedef unsigned long long u64;

__device__ __forceinline__ float u2f(u32 b){ union{u32 u; float f;} x; x.u=b; return x.f; }
__device__ __forceinline__ u32 f2u(float f){ union{u32 u; float f;} x; x.f=f; return x.u; }

// ---------------------------------------------------------------------------
// Per-row sort of transitions, desc by value, asc index on ties.
// svpT[k*KK + n] (rank-major, coalesced when all rows stream rank k)
// svpR[n*KK + k] (row-major, coalesced when one wave streams one row)
// ---------------------------------------------------------------------------
__global__ __launch_bounds__(512)
void sort_rows(const float* __restrict__ trans, u64* __restrict__ svpT,
               u64* __restrict__ svpR)
{
    __shared__ u64 s[KK];
    const int n = blockIdx.x, i = threadIdx.x;
    float x = trans[n*KK + i];
    u32 b = f2u(x);
    u32 ord = (b & 0x80000000u) ? ~b : (b | 0x80000000u);   // monotone u32 order
    s[i] = ((u64)(~ord) << 16) | (u32)i;                    // asc sort => value desc, p asc
    __syncthreads();
    for (int k = 2; k <= KK; k <<= 1){
        for (int j = k >> 1; j > 0; j >>= 1){
            int ixj = i ^ j;
            if (ixj > i){
                u64 a = s[i], c = s[ixj];
                bool up = ((i & k) == 0);
                if ((a > c) == up){ s[i] = c; s[ixj] = a; }
            }
            __syncthreads();
        }
    }
    u64 key = s[i];
    u32 p    = (u32)(key & 0xFFFFu);
    u32 ordv = ~(u32)(key >> 16);
    u32 bits = (ordv & 0x80000000u) ? (ordv ^ 0x80000000u) : ~ordv;
    u64 ent = ((u64)p << 32) | bits;
    svpT[(size_t)i*KK + n] = ent;   // rank-major
    svpR[(size_t)n*KK + i] = ent;   // row-major
}

// transT[p*KK + n] = trans[n*KK + p]
__global__ __launch_bounds__(512)
void transpose_k(const float* __restrict__ t, float* __restrict__ tt)
{
    const int c = blockIdx.x, r = threadIdx.x;
    tt[(size_t)c*KK + r] = t[(size_t)r*KK + c];
}

// ---------------------------------------------------------------------------
// Phase 1: sequential VALUE-ONLY scan (1 block, 512 threads; thread i = row i).
// Two barriers per step:
//   pre-A : publish fv; packed (fv,idx) wave argmax reduce -> wmaxS
//   A     : -> read 8 per-wave maxima; fm; ISSUE 8 transT prefetch loads for
//           the per-wave top rows (hides L2/L3 miss latency); 8 band ballots
//           (edges fm-0.5 .. fm-4.0); lane b<8 writes band masks bmS[b][wv];
//           REG16 top-16 v candidates; consume prefetch (best >= fl(fm+T[i,pmax]))
//   B     : -> band eval straight from masks: scalarized bit-walk, batches of 4
//           (pad by repeating entry 0 -- harmless for max), coalesced transT row
//           loads; bound fl(edge_b + cV[15]) <= best after each band.
//           Rare tail: wave-cooperative svpR streaming, bound fl(e7+v_last)<=best.
// Row 1 (all-NEG transitions): prefetch yields exactly fl(fm+NEG) (includes
// global argmax wave); band-0 bound fl(fm-0.5+NEG) <= fl(fm+NEG) -> done.
// Stores fm per step and boundary states every SEG steps for bp_fill.
// ---------------------------------------------------------------------------
__global__ __launch_bounds__(512)
void fv_scan(const float* __restrict__ feats,
             const u64* __restrict__ svpT,
             const u64* __restrict__ svpR,
             const float* __restrict__ transT,
             float* __restrict__ fvBound,
             float* __restrict__ fmArr,
             float* __restrict__ outScore, int* __restrict__ bestOut)
{
    __shared__ float fvb[2][KK];
    __shared__ u64  wmaxS[2][8];
    __shared__ u64  bmS[8][8];     // [band][wave]
    __shared__ float rv[KK];
    __shared__ int   ri[KK];

    const int i = threadIdx.x, lane = i & 63, wv = i >> 6;

    // top-16 (v,p) of own row in registers
    float cV[16]; int cP[16];
#pragma unroll
    for (int k = 0; k < 16; ++k){
        u64 e = svpT[(size_t)k*KK + i];
        cV[k] = u2f((u32)e); cP[k] = (int)(e >> 32);
    }
    const float cv15 = cV[15];

    // step 0 closed form: fv_init = [0, NEG..]; col 0 of trans == NEG exactly
    float fv_i = fmaxf(NEGV, NEGV + cV[0]) + feats[i];
    fvBound[i] = fv_i;                       // state(1) = segment-0 start
    float featCur = feats[(size_t)KK + i];

#define VMAX8(k0) { \
    float f0=fvc[cP[k0]],     f1=fvc[cP[(k0)+1]], f2=fvc[cP[(k0)+2]], f3=fvc[cP[(k0)+3]]; \
    float f4=fvc[cP[(k0)+4]], f5=fvc[cP[(k0)+5]], f6=fvc[cP[(k0)+6]], f7=fvc[cP[(k0)+7]]; \
    float m0=fmaxf(f0+cV[k0],     f1+cV[(k0)+1]), m1=fmaxf(f2+cV[(k0)+2], f3+cV[(k0)+3]); \
    float m2=fmaxf(f4+cV[(k0)+4], f5+cV[(k0)+5]), m3=fmaxf(f6+cV[(k0)+6], f7+cV[(k0)+7]); \
    best = fmaxf(best, fmaxf(fmaxf(m0,m1), fmaxf(m2,m3))); }

    for (int t = 1; t < TT; ++t){
        const int cur = t & 1;

        // ---------- publish fv + packed per-wave argmax ----------
        fvb[cur][i] = fv_i;
        {
            u32 ob = f2u(fv_i);
            ob = (ob & 0x80000000u) ? ~ob : (ob | 0x80000000u);
            u64 key = ((u64)ob << 32) | (u32)i;
#pragma unroll
            for (int o = 32; o > 0; o >>= 1){
                u64 ok = __shfl_xor(key, o, 64);
                key = (ok > key) ? ok : key;
            }
            if (lane == 0) wmaxS[cur][wv] = key;
        }
        __syncthreads();                                     // A

        // ---------- per-wave maxima -> fm + prefetch top-8 transT rows ------
        float wmv[8], pfv[8];
#pragma unroll
        for (int w = 0; w < 8; ++w){
            u64 kw = wmaxS[cur][w];
            u32 ov = (u32)(kw >> 32);
            u32 bits = (ov & 0x80000000u) ? (ov ^ 0x80000000u) : ~ov;
            wmv[w] = u2f(bits);
            int pw = __builtin_amdgcn_readfirstlane((int)(u32)kw);
            pfv[w] = transT[(size_t)pw*KK + i];              // issued early
        }
        float fm = wmv[0];
#pragma unroll
        for (int w = 1; w < 8; ++w) fm = fmaxf(fm, wmv[w]);
        if (i == 0) fmArr[t] = fm;

        // ---------- 8 band ballots -> per-wave masks in LDS ----------
        const float e0 = fm-0.5f, e1 = fm-1.0f, e2 = fm-1.5f, e3 = fm-2.0f;
        const float e4 = fm-2.5f, e5 = fm-3.0f, e6 = fm-3.5f, e7 = fm-4.0f;
        {
            u64 q0 = __ballot(fv_i > e0), q1 = __ballot(fv_i > e1);
            u64 q2 = __ballot(fv_i > e2), q3 = __ballot(fv_i > e3);
            u64 q4 = __ballot(fv_i > e4), q5 = __ballot(fv_i > e5);
            u64 q6 = __ballot(fv_i > e6), q7 = __ballot(fv_i > e7);
            if (lane < 8){
                u64 mb = (lane==0)? q0      : (lane==1)? (q1&~q0) :
                         (lane==2)? (q2&~q1): (lane==3)? (q3&~q2) :
                         (lane==4)? (q4&~q3): (lane==5)? (q5&~q4) :
                         (lane==6)? (q6&~q5):            (q7&~q6);
                bmS[lane][wv] = mb;
            }
        }

        // ---------- overlapped: REG16 + prefetch consume ----------
        const float* fvc = fvb[cur];
        float featNxt = __builtin_nontemporal_load(
            &feats[(size_t)(t+1 < TT ? t+1 : t)*KK + i]);
        float best = -3.0e38f;
        VMAX8(0) VMAX8(8)
#pragma unroll
        for (int w = 0; w < 8; ++w) best = fmaxf(best, wmv[w] + pfv[w]);
        __syncthreads();                                     // B

        // ---------- band eval straight from masks ----------
        bool done = false;
#pragma unroll 1
        for (int b = 0; b < 8; ++b){
            if (!__any(!done)) break;
            const float edge = fm - 0.5f*(float)(b+1);
            if (!done){
#pragma unroll 1
                for (int w = 0; w < 8; ++w){
                    u64 mraw = bmS[b][w];
                    u32 mlo = __builtin_amdgcn_readfirstlane((u32)mraw);
                    u32 mhi = __builtin_amdgcn_readfirstlane((u32)(mraw >> 32));
                    u64 m = ((u64)mhi << 32) | mlo;
                    const int pb0 = w << 6;
                    while (m){
                        int a0 = (int)__ffsll(m) - 1;  u64 mm = m & (m-1);
                        int a1 = mm ? (int)__ffsll(mm)-1 : a0;  mm &= (mm-1);
                        int a2 = mm ? (int)__ffsll(mm)-1 : a0;  mm &= (mm-1);
                        int a3 = mm ? (int)__ffsll(mm)-1 : a0;  mm &= (mm-1);
                        m = mm;
                        const int P0 = pb0+a0, P1 = pb0+a1, P2 = pb0+a2, P3 = pb0+a3;
                        float f0 = fvc[P0], f1 = fvc[P1], f2 = fvc[P2], f3 = fvc[P3];
                        float t0 = transT[(size_t)P0*KK + i];
                        float t1 = transT[(size_t)P1*KK + i];
                        float t2 = transT[(size_t)P2*KK + i];
                        float t3 = transT[(size_t)P3*KK + i];
                        best = fmaxf(best, fmaxf(fmaxf(f0+t0, f1+t1),
                                                 fmaxf(f2+t2, f3+t3)));
                    }
                }
                done = (edge + cv15 <= best);
            }
        }

        // ---------- wave-cooperative deep tail (value-only, exact) ----------
        u64 pend = __ballot(!done);
        while (pend){
            int r = (int)__ffsll((unsigned long long)pend) - 1;
            pend &= pend - 1;
            const int row = (wv << 6) + r;
            float bestR = __shfl(best, r, 64);
            int rk = 16 + lane;
            for (;;){
                float vv = -1.0e30f, sc = -1.0e30f;
                if (rk < KK){
                    u64 e = svpR[(size_t)row*KK + rk];
                    vv = u2f((u32)e);
                    sc = fvc[(int)(e >> 32)] + vv;
                }
                float m = sc;
#pragma unroll
                for (int o = 32; o > 0; o >>= 1) m = fmaxf(m, __shfl_xor(m, o, 64));
                bestR = fmaxf(bestR, m);
                float vl = __shfl(vv, 63, 64);       // smallest v this chunk
                if (e7 + vl <= bestR) break;          // uniform break
                rk += 64;
            }
            if (lane == r) best = bestR;
        }

        // ---------- finish step ----------
        fv_i = best + featCur;
        featCur = featNxt;
        if ((t & (SEG-1)) == 0)
            fvBound[(size_t)(t >> 8)*KK + i] = fv_i;  // state(t+1)
    }
#undef VMAX8

    // ---- terminal: terminal[p] = fl(fv_T[p] + NEG); first-index argmax ----
    float tv = fv_i + NEGV;
    rv[i] = tv; ri[i] = i;
    __syncthreads();
    for (int s2 = 256; s2 > 0; s2 >>= 1){
        if (i < s2){
            float v2 = rv[i+s2]; int i2 = ri[i+s2];
            if (v2 > rv[i] || (v2 == rv[i] && i2 < ri[i])){ rv[i] = v2; ri[i] = i2; }
        }
        __syncthreads();
    }
    if (i == 0){ outScore[0] = rv[0]; *bestOut = ri[0]; }
}

// ---------------------------------------------------------------------------
// Phase 2: parallel backpointer fill. Block s re-runs segment s (SEG steps)
// from the stored boundary state (bit-exact) and computes bp[t][i] with
// reference-exact first-index-tie argmax: rank-scan svpT with strict bound
// fl(fm + v_next) < best (continue on equality => ties never skipped).
// Row 1 (all v == NEG) special-cased exactly: max = fl(fm+NEG); argmax =
// first-index argmax of ROUNDED fl(fv[p]+NEG) via block reduce, min-index tie.
// ---------------------------------------------------------------------------
__global__ __launch_bounds__(512)
void bp_fill(const float* __restrict__ feats,
             const u64* __restrict__ svpT,
             const float* __restrict__ fvBound,
             const float* __restrict__ fmArr,
             u16* __restrict__ bp)
{
    __shared__ float fvb[2][KK];
    __shared__ u64  r1S[2][8];
    const int i = threadIdx.x, lane = i & 63, wv = i >> 6;
    const int s = blockIdx.x;
    const int t0 = s*SEG + 1;
    const int tEnd = (s == NSEG-1) ? (TT-1) : (s*SEG + SEG);

    float fv_i = fvBound[(size_t)s*KK + i];
    float featC = feats[(size_t)t0*KK + i];

#define TAKE(p_, val_) { float _val=(val_); int _p=(p_); \
    bool _tk = (_val > best) || (_val == best && _p < barg); \
    best = _tk ? _val : best; barg = _tk ? _p : barg; }

    for (int t = t0; t <= tEnd; ++t){
        const int cur = t & 1;
        fvb[cur][i] = fv_i;
        // row-1 argmax key: rounded score fl(fv+NEG), min-p tie -> max key
        float sc1 = fv_i + NEGV;
        u32 bb = f2u(sc1);
        u32 od = (bb & 0x80000000u) ? ~bb : (bb | 0x80000000u);
        u64 key = ((u64)od << 32) | (u32)(KK - 1 - i);
#pragma unroll
        for (int o = 32; o > 0; o >>= 1){
            u64 ok = __shfl_xor(key, o, 64);
            key = (ok > key) ? ok : key;
        }
        if (lane == 0) r1S[cur][wv] = key;
        float featN = (t < tEnd) ? feats[(size_t)(t+1)*KK + i] : 0.0f;
        __syncthreads();
        const float fm = fmArr[t];
        const float* fvc = fvb[cur];
        float best; int barg;
        if (i == 1){
            u64 kk = r1S[cur][0];
#pragma unroll
            for (int w = 1; w < 8; ++w){ u64 o2 = r1S[cur][w]; kk = (o2 > kk) ? o2 : kk; }
            barg = (KK - 1) - (int)(u32)kk;
            best = fm + NEGV;
        } else {
            best = -3.0e38f; barg = 0;
            for (int kb = 0; kb < KK; kb += 8){
                const u64* sp = &svpT[(size_t)kb*KK + i];
                u64 E0 = sp[0];          u64 E1 = sp[(size_t)KK];
                u64 E2 = sp[(size_t)2*KK]; u64 E3 = sp[(size_t)3*KK];
                u64 E4 = sp[(size_t)4*KK]; u64 E5 = sp[(size_t)5*KK];
                u64 E6 = sp[(size_t)6*KK]; u64 E7 = sp[(size_t)7*KK];
                int p0=(int)(E0>>32), p1=(int)(E1>>32), p2=(int)(E2>>32), p3=(int)(E3>>32);
                int p4=(int)(E4>>32), p5=(int)(E5>>32), p6=(int)(E6>>32), p7=(int)(E7>>32);
                TAKE(p0, fvc[p0] + u2f((u32)E0)); TAKE(p1, fvc[p1] + u2f((u32)E1));
                TAKE(p2, fvc[p2] + u2f((u32)E2)); TAKE(p3, fvc[p3] + u2f((u32)E3));
                TAKE(p4, fvc[p4] + u2f((u32)E4)); TAKE(p5, fvc[p5] + u2f((u32)E5));
                TAKE(p6, fvc[p6] + u2f((u32)E6)); TAKE(p7, fvc[p7] + u2f((u32)E7));
                float vlast = u2f((u32)E7);
                if (fm + vlast < best) break;   // strict: equality could tie later
            }
        }
        __builtin_nontemporal_store((u16)barg, &bp[(size_t)t*KK + i]);
        fv_i = best + featC;
        featC = featN;
    }
#undef TAKE
}

// ---------------------------------------------------------------------------
// Backtrack: segment maps (parallel) -> boundary tags -> per-segment decode.
// ---------------------------------------------------------------------------
__global__ __launch_bounds__(512)
void bt_maps(const u16* __restrict__ bp, u16* __restrict__ maps)
{
    const int s = blockIdx.x, e = threadIdx.x;
    const int tEnd = (s == NSEG-1) ? (TT-1) : (s+1)*SEG;
    const int tLow = s*SEG;
    int cur = e;
    for (int t = tEnd; t > tLow; --t) cur = (int)bp[(size_t)t*KK + cur];
    maps[s*KK + e] = (u16)cur;
}

__global__ void bt_boundaries(const u16* __restrict__ maps, const int* __restrict__ bestP,
                              int* __restrict__ btag)
{
    if (threadIdx.x != 0 || blockIdx.x != 0) return;
    int cur = *bestP;
    for (int s = NSEG-1; s >= 0; --s){
        cur = (int)maps[s*KK + cur];
        btag[s] = cur;
    }
}

__global__ void bt_decode(const u16* __restrict__ bp, const int* __restrict__ btag,
                          const int* __restrict__ bestP, float* __restrict__ outPath)
{
    const int s = blockIdx.x;
    if (threadIdx.x != 0) return;
    int tEnd, cur;
    if (s == NSEG-1){ tEnd = TT-1; cur = *bestP; outPath[TT-1] = (float)cur; }
    else            { tEnd = (s+1)*SEG; cur = btag[s+1]; }
    for (int t = tEnd; t > s*SEG; --t){
        cur = (int)bp[(size_t)t*KK + cur];
        outPath[t-1] = (float)cur;
    }
}

// ---------------------------------------------------------------------------
extern "C" void kernel_launch(void* const* d_in, const int* in_sizes, int n_in,
                              void* d_out, int out_size, void* d_ws, size_t ws_size,
                              hipStream_t stream)
{
    (void)in_sizes; (void)n_in; (void)out_size; (void)ws_size;
    const float* feats = (const float*)d_in[0];
    const float* trans = (const float*)d_in[1];
    float* out = (float*)d_out;

    char* ws = (char*)d_ws;
    size_t off = 0;
    u16*   bp     = (u16*)(ws + off);   off += (size_t)TT*KK*sizeof(u16);    // 64 MB
    u64*   svpT   = (u64*)(ws + off);   off += (size_t)KK*KK*sizeof(u64);    // 2 MB
    u64*   svpR   = (u64*)(ws + off);   off += (size_t)KK*KK*sizeof(u64);    // 2 MB
    float* transT = (float*)(ws + off); off += (size_t)KK*KK*sizeof(float);  // 1 MB
    float* fvBound= (float*)(ws + off); off += (size_t)NSEG*KK*sizeof(float);// 512 KB
    float* fmArr  = (float*)(ws + off); off += (size_t)TT*sizeof(float);     // 256 KB
    u16*   maps   = (u16*)(ws + off);   off += (size_t)NSEG*KK*sizeof(u16);  // 256 KB
    int*   btag   = (int*)(ws + off);   off += (size_t)(NSEG+8)*sizeof(int);
    int*   bestP  = (int*)(ws + off);

    hipLaunchKernelGGL(sort_rows,     dim3(KK),   dim3(512), 0, stream, trans, svpT, svpR);
    hipLaunchKernelGGL(transpose_k,   dim3(KK),   dim3(512), 0, stream, trans, transT);
    hipLaunchKernelGGL(fv_scan,       dim3(1),    dim3(512), 0, stream, feats, svpT, svpR,
                       transT, fvBound, fmArr, out, bestP);
    hipLaunchKernelGGL(bp_fill,       dim3(NSEG), dim3(512), 0, stream, feats, svpT,
                       fvBound, fmArr, bp);
    hipLaunchKernelGGL(bt_maps,       dim3(NSEG), dim3(512), 0, stream, bp, maps);
    hipLaunchKernelGGL(bt_boundaries, dim3(1),    dim3(64),  0, stream, maps, bestP, btag);
    hipLaunchKernelGGL(bt_decode,     dim3(NSEG), dim3(64),  0, stream, bp, btag, bestP, out + 1);
}

// Round 3
// 361728.369 us; speedup vs baseline: 1.7598x; 1.7598x over previous
//
#include <hip/hip_runtime.h>
#include <cstdint>
#include <cstddef>

#define TT 65536
#define KK 512
#define NEGV (-10000.0f)
#define SEG 256
#define NSEG 256  // TT/SEG
#define BCAP 256  // per-band list capacity (overflow -> exact fm-bound fallback)

typedef unsigned short u16;
typedef unsigned int   u32;
typedef unsigned long long u64;

__device__ __forceinline__ float u2f(u32 b){ union{u32 u; float f;} x; x.u=b; return x.f; }
__device__ __forceinline__ u32 f2u(float f){ union{u32 u; float f;} x; x.f=f; return x.u; }

// ---------------------------------------------------------------------------
// Per-row sort of transitions, desc by value, asc index on ties.
// svpT[k*KK + n] (rank-major, coalesced when all rows stream rank k)
// svpR[n*KK + k] (row-major, coalesced when one wave streams one row)
// ---------------------------------------------------------------------------
__global__ __launch_bounds__(512)
void sort_rows(const float* __restrict__ trans, u64* __restrict__ svpT,
               u64* __restrict__ svpR)
{
    __shared__ u64 s[KK];
    const int n = blockIdx.x, i = threadIdx.x;
    float x = trans[n*KK + i];
    u32 b = f2u(x);
    u32 ord = (b & 0x80000000u) ? ~b : (b | 0x80000000u);   // monotone u32 order
    s[i] = ((u64)(~ord) << 16) | (u32)i;                    // asc sort => value desc, p asc
    __syncthreads();
    for (int k = 2; k <= KK; k <<= 1){
        for (int j = k >> 1; j > 0; j >>= 1){
            int ixj = i ^ j;
            if (ixj > i){
                u64 a = s[i], c = s[ixj];
                bool up = ((i & k) == 0);
                if ((a > c) == up){ s[i] = c; s[ixj] = a; }
            }
            __syncthreads();
        }
    }
    u64 key = s[i];
    u32 p    = (u32)(key & 0xFFFFu);
    u32 ordv = ~(u32)(key >> 16);
    u32 bits = (ordv & 0x80000000u) ? (ordv ^ 0x80000000u) : ~ordv;
    u64 ent = ((u64)p << 32) | bits;
    svpT[(size_t)i*KK + n] = ent;   // rank-major
    svpR[(size_t)n*KK + i] = ent;   // row-major
}

// transT[p*KK + n] = trans[n*KK + p]
__global__ __launch_bounds__(512)
void transpose_k(const float* __restrict__ t, float* __restrict__ tt)
{
    const int c = blockIdx.x, r = threadIdx.x;
    tt[(size_t)c*KK + r] = t[(size_t)r*KK + c];
}

// ---------------------------------------------------------------------------
// Phase 1: sequential VALUE-ONLY scan (1 block, 512 threads; thread i = row i).
// Two barriers per step:
//   pre-A : publish fv; packed (fv,idx) wave argmax reduce -> wmaxS
//   A     : read 8 per-wave (max,arg); fm; ISSUE 8 coalesced transT prefetch
//           loads for the per-wave argmax rows (warm start, hides L3 latency);
//           zero next-parity counters; band classify fv into 6 bands
//           (edges fm-0.5 .. fm-3.0), LDS-atomic slot -> dense per-band lists
//           (order within band irrelevant: value-only fmax); REG16 top-16 v
//           candidates; consume prefetch (best >= fl(fm+T[i,p_w]))
//   B     : band eval over dense lists, padded batches of 8 (broadcast LDS
//           entry reads + coalesced transT loads all issued up front); bound
//           fl(edge_b + cV[15]) <= best after each fully-consumed band.
//           Rare tail: wave-cooperative svpR streaming from rank 16, bound
//           fl(eT + v_last) <= best, eT = fm-3.0 (or fm on CAP overflow).
// Row 1 (all-NEG transitions): prefetch gives exactly fl(fm+NEG) (monotone fl
// over the 8 wave maxima incl. the global max); band-0 bound
// fl(fm-0.5+NEG) <= fl(fm+NEG) -> done immediately.
// Stores fm per step and boundary states every SEG steps for bp_fill.
// ---------------------------------------------------------------------------
__global__ __launch_bounds__(512)
void fv_scan(const float* __restrict__ feats,
             const u64* __restrict__ svpT,
             const u64* __restrict__ svpR,
             const float* __restrict__ transT,
             float* __restrict__ fvBound,
             float* __restrict__ fmArr,
             float* __restrict__ outScore, int* __restrict__ bestOut)
{
    __shared__ float fvb[2][KK];
    __shared__ u64  wmaxS[2][8];
    __shared__ int  cntS[2][8];
    __shared__ u64  bandL[6][BCAP];
    __shared__ float rv[KK];
    __shared__ int   ri[KK];

    const int i = threadIdx.x, lane = i & 63, wv = i >> 6;

    // top-16 (v,p) of own row in registers
    float cV[16]; int cP[16];
#pragma unroll
    for (int k = 0; k < 16; ++k){
        u64 e = svpT[(size_t)k*KK + i];
        cV[k] = u2f((u32)e); cP[k] = (int)(e >> 32);
    }
    const float cv15 = cV[15];

    if (i < 8){ cntS[0][i] = 0; cntS[1][i] = 0; }

    // step 0 closed form: fv_init = [0, NEG..]; col 0 of trans == NEG exactly
    float fv_i = fmaxf(NEGV, NEGV + cV[0]) + feats[i];
    fvBound[i] = fv_i;                       // state(1) = segment-0 start
    float featCur = feats[(size_t)KK + i];

#define VMAX8(k0) { \
    float f0=fvc[cP[k0]],     f1=fvc[cP[(k0)+1]], f2=fvc[cP[(k0)+2]], f3=fvc[cP[(k0)+3]]; \
    float f4=fvc[cP[(k0)+4]], f5=fvc[cP[(k0)+5]], f6=fvc[cP[(k0)+6]], f7=fvc[cP[(k0)+7]]; \
    float m0=fmaxf(f0+cV[k0],     f1+cV[(k0)+1]), m1=fmaxf(f2+cV[(k0)+2], f3+cV[(k0)+3]); \
    float m2=fmaxf(f4+cV[(k0)+4], f5=f5+cV[(k0)+5], m2), m3=fmaxf(f6+cV[(k0)+6], f7+cV[(k0)+7]); \
    best = fmaxf(best, fmaxf(fmaxf(m0,m1), fmaxf(m2,m3))); }
#undef VMAX8
#define VMAX8(k0) { \
    float f0=fvc[cP[k0]],     f1=fvc[cP[(k0)+1]], f2=fvc[cP[(k0)+2]], f3=fvc[cP[(k0)+3]]; \
    float f4=fvc[cP[(k0)+4]], f5=fvc[cP[(k0)+5]], f6=fvc[cP[(k0)+6]], f7=fvc[cP[(k0)+7]]; \
    float m0=fmaxf(f0+cV[k0],     f1+cV[(k0)+1]), m1=fmaxf(f2+cV[(k0)+2], f3+cV[(k0)+3]); \
    float m2=fmaxf(f4+cV[(k0)+4], f5+cV[(k0)+5]), m3=fmaxf(f6+cV[(k0)+6], f7+cV[(k0)+7]); \
    best = fmaxf(best, fmaxf(fmaxf(m0,m1), fmaxf(m2,m3))); }

    for (int t = 1; t < TT; ++t){
        const int cur = t & 1;

        // ---------- publish fv + packed (fv,idx) wave argmax ----------
        fvb[cur][i] = fv_i;
        {
            u32 ob = f2u(fv_i);
            ob = (ob & 0x80000000u) ? ~ob : (ob | 0x80000000u);
            u64 key = ((u64)ob << 32) | (u32)i;
#pragma unroll
            for (int o = 32; o > 0; o >>= 1){
                u64 ok = __shfl_xor(key, o, 64);
                key = (ok > key) ? ok : key;
            }
            if (lane == 0) wmaxS[cur][wv] = key;
        }
        __syncthreads();                                     // A

        // ---------- per-wave (max,arg) -> fm + 8-row transT prefetch ----------
        float wmv[8], pfv[8];
#pragma unroll
        for (int w = 0; w < 8; ++w){
            u64 kw = wmaxS[cur][w];
            u32 ov = (u32)(kw >> 32);
            u32 bits = (ov & 0x80000000u) ? (ov ^ 0x80000000u) : ~ov;
            wmv[w] = u2f(bits);
            int pw = __builtin_amdgcn_readfirstlane((int)(u32)kw);
            pfv[w] = transT[(size_t)pw*KK + i];              // issued early
        }
        float fm = wmv[0];
#pragma unroll
        for (int w = 1; w < 8; ++w) fm = fmaxf(fm, wmv[w]);
        if (i == 0) fmArr[t] = fm;
        if (i < 8) cntS[cur^1][i] = 0;    // zero counters for step t+1 (sync: A of t+1)

        // ---------- band classify + atomic slot into dense lists ----------
        const float e0=fm-0.5f, e1=fm-1.0f, e2=fm-1.5f, e3=fm-2.0f, e4=fm-2.5f, e5=fm-3.0f;
        int b_i = (fv_i > e0)?0:(fv_i > e1)?1:(fv_i > e2)?2:
                  (fv_i > e3)?3:(fv_i > e4)?4:(fv_i > e5)?5:6;
        if (b_i < 6){
            int slot = atomicAdd(&cntS[cur][b_i], 1);
            if (slot < BCAP) bandL[b_i][slot] = ((u64)f2u(fv_i) << 32) | (u32)i;
        }

        // ---------- overlapped: REG16 + prefetch consume ----------
        const float* fvc = fvb[cur];
        float featNxt = __builtin_nontemporal_load(
            &feats[(size_t)(t+1 < TT ? t+1 : t)*KK + i]);
        float best = -3.0e38f;
        VMAX8(0) VMAX8(8)
#pragma unroll
        for (int w = 0; w < 8; ++w) best = fmaxf(best, wmv[w] + pfv[w]);
        __syncthreads();                                     // B

        // ---------- band eval over dense lists ----------
        bool done = false, ovfc = false;
#pragma unroll 1
        for (int b = 0; b < 6; ++b){
            if (!__any(!done)) break;
            int cb = __builtin_amdgcn_readfirstlane(cntS[cur][b]);
            int nb = cb > BCAP ? BCAP : cb;
            const float edge = fm - 0.5f*(float)(b+1);
            if (!done && nb > 0){
                const u64* BL = &bandL[b][0];
                const int nlast = nb - 1;
#pragma unroll 1
                for (int u = 0; u < nb; u += 8){
                    int j1=u+1, j2=u+2, j3=u+3, j4=u+4, j5=u+5, j6=u+6, j7=u+7;
                    j1 = j1>nlast?nlast:j1; j2 = j2>nlast?nlast:j2;
                    j3 = j3>nlast?nlast:j3; j4 = j4>nlast?nlast:j4;
                    j5 = j5>nlast?nlast:j5; j6 = j6>nlast?nlast:j6;
                    j7 = j7>nlast?nlast:j7;
                    u64 E0=BL[u],  E1=BL[j1], E2=BL[j2], E3=BL[j3];
                    u64 E4=BL[j4], E5=BL[j5], E6=BL[j6], E7=BL[j7];
                    int P0=(int)(E0&0xFFFFu), P1=(int)(E1&0xFFFFu);
                    int P2=(int)(E2&0xFFFFu), P3=(int)(E3&0xFFFFu);
                    int P4=(int)(E4&0xFFFFu), P5=(int)(E5&0xFFFFu);
                    int P6=(int)(E6&0xFFFFu), P7=(int)(E7&0xFFFFu);
                    float T0=transT[(size_t)P0*KK+i], T1=transT[(size_t)P1*KK+i];
                    float T2=transT[(size_t)P2*KK+i], T3=transT[(size_t)P3*KK+i];
                    float T4=transT[(size_t)P4*KK+i], T5=transT[(size_t)P5*KK+i];
                    float T6=transT[(size_t)P6*KK+i], T7=transT[(size_t)P7*KK+i];
                    float F0=u2f((u32)(E0>>32)), F1=u2f((u32)(E1>>32));
                    float F2=u2f((u32)(E2>>32)), F3=u2f((u32)(E3>>32));
                    float F4=u2f((u32)(E4>>32)), F5=u2f((u32)(E5>>32));
                    float F6=u2f((u32)(E6>>32)), F7=u2f((u32)(E7>>32));
                    float m0=fmaxf(F0+T0,F1+T1), m1=fmaxf(F2+T2,F3+T3);
                    float m2=fmaxf(F4+T4,F5+T5), m3=fmaxf(F6+T6,F7+T7);
                    best = fmaxf(best, fmaxf(fmaxf(m0,m1), fmaxf(m2,m3)));
                }
            }
            ovfc = ovfc || (cb > BCAP);
            if (!ovfc) done = done || (edge + cv15 <= best);
        }

        // ---------- wave-cooperative deep tail (value-only, exact) ----------
        // Unseen p beyond rank kc: v <= v_last; fv <= fm-3.0 (bands complete)
        // or <= fm (overflow fallback). REG16 covered ranks 0..15.
        const float eT = ovfc ? fm : e5;
        u64 pend = __ballot(!done);
        while (pend){
            int r = (int)__ffsll((unsigned long long)pend) - 1;
            pend &= pend - 1;
            const int row = (wv << 6) + r;
            float bestR = __shfl(best, r, 64);
            int rk = 16 + lane;
            for (;;){
                float vv = -1.0e30f, sc = -1.0e30f;
                if (rk < KK){
                    u64 e = svpR[(size_t)row*KK + rk];
                    vv = u2f((u32)e);
                    sc = fvc[(int)(e >> 32)] + vv;
                }
                float m = sc;
#pragma unroll
                for (int o = 32; o > 0; o >>= 1) m = fmaxf(m, __shfl_xor(m, o, 64));
                bestR = fmaxf(bestR, m);
                float vl = __shfl(vv, 63, 64);       // smallest v this chunk
                if (eT + vl <= bestR) break;          // uniform break
                rk += 64;
            }
            if (lane == r) best = bestR;
        }

        // ---------- finish step ----------
        fv_i = best + featCur;
        featCur = featNxt;
        if ((t & (SEG-1)) == 0)
            fvBound[(size_t)(t >> 8)*KK + i] = fv_i;  // state(t+1)
    }
#undef VMAX8

    // ---- terminal: terminal[p] = fl(fv_T[p] + NEG); first-index argmax ----
    float tv = fv_i + NEGV;
    rv[i] = tv; ri[i] = i;
    __syncthreads();
    for (int s2 = 256; s2 > 0; s2 >>= 1){
        if (i < s2){
            float v2 = rv[i+s2]; int i2 = ri[i+s2];
            if (v2 > rv[i] || (v2 == rv[i] && i2 < ri[i])){ rv[i] = v2; ri[i] = i2; }
        }
        __syncthreads();
    }
    if (i == 0){ outScore[0] = rv[0]; *bestOut = ri[0]; }
}

// ---------------------------------------------------------------------------
// Phase 2: parallel backpointer fill. Block s re-runs segment s (SEG steps)
// from the stored boundary state (bit-exact) and computes bp[t][i] with
// reference-exact first-index-tie argmax: rank-scan svpT with strict bound
// fl(fm + v_next) < best (continue on equality => ties never skipped).
// Row 1 (all v == NEG) special-cased exactly: max = fl(fm+NEG); argmax =
// first-index argmax of ROUNDED fl(fv[p]+NEG) via block reduce, min-index tie.
// ---------------------------------------------------------------------------
__global__ __launch_bounds__(512)
void bp_fill(const float* __restrict__ feats,
             const u64* __restrict__ svpT,
             const float* __restrict__ fvBound,
             const float* __restrict__ fmArr,
             u16* __restrict__ bp)
{
    __shared__ float fvb[2][KK];
    __shared__ u64  r1S[2][8];
    const int i = threadIdx.x, lane = i & 63, wv = i >> 6;
    const int s = blockIdx.x;
    const int t0 = s*SEG + 1;
    const int tEnd = (s == NSEG-1) ? (TT-1) : (s*SEG + SEG);

    float fv_i = fvBound[(size_t)s*KK + i];
    float featC = feats[(size_t)t0*KK + i];

#define TAKE(p_, val_) { float _val=(val_); int _p=(p_); \
    bool _tk = (_val > best) || (_val == best && _p < barg); \
    best = _tk ? _val : best; barg = _tk ? _p : barg; }

    for (int t = t0; t <= tEnd; ++t){
        const int cur = t & 1;
        fvb[cur][i] = fv_i;
        // row-1 argmax key: rounded score fl(fv+NEG), min-p tie -> max key
        float sc1 = fv_i + NEGV;
        u32 bb = f2u(sc1);
        u32 od = (bb & 0x80000000u) ? ~bb : (bb | 0x80000000u);
        u64 key = ((u64)od << 32) | (u32)(KK - 1 - i);
#pragma unroll
        for (int o = 32; o > 0; o >>= 1){
            u64 ok = __shfl_xor(key, o, 64);
            key = (ok > key) ? ok : key;
        }
        if (lane == 0) r1S[cur][wv] = key;
        float featN = (t < tEnd) ? feats[(size_t)(t+1)*KK + i] : 0.0f;
        __syncthreads();
        const float fm = fmArr[t];
        const float* fvc = fvb[cur];
        float best; int barg;
        if (i == 1){
            u64 kk = r1S[cur][0];
#pragma unroll
            for (int w = 1; w < 8; ++w){ u64 o2 = r1S[cur][w]; kk = (o2 > kk) ? o2 : kk; }
            barg = (KK - 1) - (int)(u32)kk;
            best = fm + NEGV;
        } else {
            best = -3.0e38f; barg = 0;
            for (int kb = 0; kb < KK; kb += 8){
                const u64* sp = &svpT[(size_t)kb*KK + i];
                u64 E0 = sp[0];          u64 E1 = sp[(size_t)KK];
                u64 E2 = sp[(size_t)2*KK]; u64 E3 = sp[(size_t)3*KK];
                u64 E4 = sp[(size_t)4*KK]; u64 E5 = sp[(size_t)5*KK];
                u64 E6 = sp[(size_t)6*KK]; u64 E7 = sp[(size_t)7*KK];
                int p0=(int)(E0>>32), p1=(int)(E1>>32), p2=(int)(E2>>32), p3=(int)(E3>>32);
                int p4=(int)(E4>>32), p5=(int)(E5>>32), p6=(int)(E6>>32), p7=(int)(E7>>32);
                TAKE(p0, fvc[p0] + u2f((u32)E0)); TAKE(p1, fvc[p1] + u2f((u32)E1));
                TAKE(p2, fvc[p2] + u2f((u32)E2)); TAKE(p3, fvc[p3] + u2f((u32)E3));
                TAKE(p4, fvc[p4] + u2f((u32)E4)); TAKE(p5, fvc[p5] + u2f((u32)E5));
                TAKE(p6, fvc[p6] + u2f((u32)E6)); TAKE(p7, fvc[p7] + u2f((u32)E7));
                float vlast = u2f((u32)E7);
                if (fm + vlast < best) break;   // strict: equality could tie later
            }
        }
        __builtin_nontemporal_store((u16)barg, &bp[(size_t)t*KK + i]);
        fv_i = best + featC;
        featC = featN;
    }
#undef TAKE
}

// ---------------------------------------------------------------------------
// Backtrack: segment maps (parallel) -> boundary tags -> per-segment decode.
// ---------------------------------------------------------------------------
__global__ __launch_bounds__(512)
void bt_maps(const u16* __restrict__ bp, u16* __restrict__ maps)
{
    const int s = blockIdx.x, e = threadIdx.x;
    const int tEnd = (s == NSEG-1) ? (TT-1) : (s+1)*SEG;
    const int tLow = s*SEG;
    int cur = e;
    for (int t = tEnd; t > tLow; --t) cur = (int)bp[(size_t)t*KK + cur];
    maps[s*KK + e] = (u16)cur;
}

__global__ void bt_boundaries(const u16* __restrict__ maps, const int* __restrict__ bestP,
                              int* __restrict__ btag)
{
    if (threadIdx.x != 0 || blockIdx.x != 0) return;
    int cur = *bestP;
    for (int s = NSEG-1; s >= 0; --s){
        cur = (int)maps[s*KK + cur];
        btag[s] = cur;
    }
}

__global__ void bt_decode(const u16* __restrict__ bp, const int* __restrict__ btag,
                          const int* __restrict__ bestP, float* __restrict__ outPath)
{
    const int s = blockIdx.x;
    if (threadIdx.x != 0) return;
    int tEnd, cur;
    if (s == NSEG-1){ tEnd = TT-1; cur = *bestP; outPath[TT-1] = (float)cur; }
    else            { tEnd = (s+1)*SEG; cur = btag[s+1]; }
    for (int t = tEnd; t > s*SEG; --t){
        cur = (int)bp[(size_t)t*KK + cur];
        outPath[t-1] = (float)cur;
    }
}

// ---------------------------------------------------------------------------
extern "C" void kernel_launch(void* const* d_in, const int* in_sizes, int n_in,
                              void* d_out, int out_size, void* d_ws, size_t ws_size,
                              hipStream_t stream)
{
    (void)in_sizes; (void)n_in; (void)out_size; (void)ws_size;
    const float* feats = (const float*)d_in[0];
    const float* trans = (const float*)d_in[1];
    float* out = (float*)d_out;

    char* ws = (char*)d_ws;
    size_t off = 0;
    u16*   bp     = (u16*)(ws + off);   off += (size_t)TT*KK*sizeof(u16);    // 64 MB
    u64*   svpT   = (u64*)(ws + off);   off += (size_t)KK*KK*sizeof(u64);    // 2 MB
    u64*   svpR   = (u64*)(ws + off);   off += (size_t)KK*KK*sizeof(u64);    // 2 MB
    float* transT = (float*)(ws + off); off += (size_t)KK*KK*sizeof(float);  // 1 MB
    float* fvBound= (float*)(ws + off); off += (size_t)NSEG*KK*sizeof(float);// 512 KB
    float* fmArr  = (float*)(ws + off); off += (size_t)TT*sizeof(float);     // 256 KB
    u16*   maps   = (u16*)(ws + off);   off += (size_t)NSEG*KK*sizeof(u16);  // 256 KB
    int*   btag   = (int*)(ws + off);   off += (size_t)(NSEG+8)*sizeof(int);
    int*   bestP  = (int*)(ws + off);

    hipLaunchKernelGGL(sort_rows,     dim3(KK),   dim3(512), 0, stream, trans, svpT, svpR);
    hipLaunchKernelGGL(transpose_k,   dim3(KK),   dim3(512), 0, stream, trans, transT);
    hipLaunchKernelGGL(fv_scan,       dim3(1),    dim3(512), 0, stream, feats, svpT, svpR,
                       transT, fvBound, fmArr, out, bestP);
    hipLaunchKernelGGL(bp_fill,       dim3(NSEG), dim3(512), 0, stream, feats, svpT,
                       fvBound, fmArr, bp);
    hipLaunchKernelGGL(bt_maps,       dim3(NSEG), dim3(512), 0, stream, bp, maps);
    hipLaunchKernelGGL(bt_boundaries, dim3(1),    dim3(64),  0, stream, maps, bestP, btag);
    hipLaunchKernelGGL(bt_decode,     dim3(NSEG), dim3(64),  0, stream, bp, btag, bestP, out + 1);
}